// Round 10
// baseline (118.594 us; speedup 1.0000x reference)
//
#include <hip/hip_runtime.h>

typedef float f32x4 __attribute__((ext_vector_type(4)));
typedef _Float16 f16;
typedef f16 f16x8 __attribute__((ext_vector_type(8)));

#define MAXDEG 56
#define OVF_CAP 4096

// out[e] = relu(relu(features[src[e]] @ W1 + b1) @ W2 + b2)
// Broadcast formulation: bucket edges by source node (ws slot table), then one
// kernel MFMA-computes each node's MLP row ONCE and pushes it to all its edges.
// Per-edge memory cost: 4B eid read + 256B write (vs 128-256B gathered reads
// before). The 205MB output stream becomes write-only -> fill-kernel BW.
//
// ws layout (u32 words): [cnt: N][ovf_cnt: 1][pad: 15][slots: N*MAXDEG][ovf: OVF_CAP]

// ---------------- bucket edges by source node ----------------
__global__ __launch_bounds__(256) void fill_slots_kernel(
    const int* __restrict__ src, unsigned* __restrict__ cnt,
    unsigned* __restrict__ slots, unsigned* __restrict__ ovf,
    unsigned* __restrict__ ovfc, int E)
{
    const int stride = gridDim.x * blockDim.x;
    for (int e = blockIdx.x * blockDim.x + threadIdx.x; e < E; e += stride) {
        const int n = src[e];
        const unsigned slot = atomicAdd(&cnt[n], 1u);
        if (slot < MAXDEG) {
            slots[(long long)n * MAXDEG + slot] = (unsigned)e;
        } else {
            const unsigned o = atomicAdd(ovfc, 1u);
            if (o < OVF_CAP) ovf[o] = (unsigned)e;
        }
    }
}

// ---------------- fused MLP + broadcast ----------------
// Per wave, per 16-row tile: MFMA 2-layer MLP (layouts proven in R6-R8),
// Y-tile staged in wave-private LDS, then pushed to edges 4-at-a-time
// (lane group q handles edge base+q; 16 lanes x 16B = 256B per edge).
__global__ __launch_bounds__(256) void bcast_kernel(
    const float* __restrict__ feat,  // [N][64] f32
    const int* __restrict__ src,     // [E]
    const float* __restrict__ W1, const float* __restrict__ b1,
    const float* __restrict__ W2, const float* __restrict__ b2,
    const unsigned* __restrict__ cnt,
    const unsigned* __restrict__ slots,
    const unsigned* __restrict__ ovf,
    const unsigned* __restrict__ ovfc,
    float* __restrict__ out, int N, int E)
{
    __shared__ f16   hl[4][16][72];  // h transpose staging, per wave
    __shared__ float ol[4][16][68];  // Y-tile staging, per wave
    __shared__ int   se[4][16];      // overflow-phase edge ids, per wave

    const int lane = threadIdx.x & 63;
    const int wv   = threadIdx.x >> 6;
    const int l15  = lane & 15;
    const int q    = lane >> 4;

    const int gw = blockIdx.x * 4 + wv;
    const int nw = gridDim.x * 4;

    // Weight fragments in registers for the whole kernel.
    f16x8 B1f[4][2], B2f[4][2];
    #pragma unroll
    for (int t = 0; t < 4; ++t) {
        #pragma unroll
        for (int s = 0; s < 2; ++s) {
            f16x8 r1, r2;
            #pragma unroll
            for (int j = 0; j < 8; ++j) {
                const int kk = s * 32 + q * 8 + j;
                r1[j] = (f16)W1[kk * 64 + t * 16 + l15];
                r2[j] = (f16)W2[kk * 64 + t * 16 + l15];
            }
            B1f[t][s] = r1;
            B2f[t][s] = r2;
        }
    }
    float bb1[4], bb2[4];
    #pragma unroll
    for (int t = 0; t < 4; ++t) {
        bb1[t] = b1[t * 16 + l15];
        bb2[t] = b2[t * 16 + l15];
    }

    // ---- main: per-node tiles ----
    const int ntile = (N + 15) >> 4;
    for (int tile = gw; tile < ntile; tile += nw) {
        const int r0 = tile << 4;
        const int rr = (r0 + l15 < N) ? (r0 + l15) : (N - 1);
        const float* p = feat + (long long)rr * 64;

        f16x8 A0, A1;
        {
            const f32x4 u0 = *(const f32x4*)(p + q * 8);
            const f32x4 u1 = *(const f32x4*)(p + q * 8 + 4);
            const f32x4 u2 = *(const f32x4*)(p + 32 + q * 8);
            const f32x4 u3 = *(const f32x4*)(p + 32 + q * 8 + 4);
            #pragma unroll
            for (int j = 0; j < 4; ++j) {
                A0[j] = (f16)u0[j]; A0[4 + j] = (f16)u1[j];
                A1[j] = (f16)u2[j]; A1[4 + j] = (f16)u3[j];
            }
        }

        // Layer 1.
        f32x4 acc[4];
        #pragma unroll
        for (int t = 0; t < 4; ++t) acc[t] = (f32x4){bb1[t], bb1[t], bb1[t], bb1[t]};
        #pragma unroll
        for (int t = 0; t < 4; ++t) {
            acc[t] = __builtin_amdgcn_mfma_f32_16x16x32_f16(A0, B1f[t][0], acc[t], 0, 0, 0);
            acc[t] = __builtin_amdgcn_mfma_f32_16x16x32_f16(A1, B1f[t][1], acc[t], 0, 0, 0);
        }
        #pragma unroll
        for (int t = 0; t < 4; ++t)
            #pragma unroll
            for (int i = 0; i < 4; ++i)
                hl[wv][q * 4 + i][t * 16 + l15] = (f16)fmaxf(acc[t][i], 0.0f);

        const f16x8 A2a = *(const f16x8*)&hl[wv][l15][q * 8];
        const f16x8 A2b = *(const f16x8*)&hl[wv][l15][32 + q * 8];

        // Layer 2.
        f32x4 acc2[4];
        #pragma unroll
        for (int t = 0; t < 4; ++t) acc2[t] = (f32x4){bb2[t], bb2[t], bb2[t], bb2[t]};
        #pragma unroll
        for (int t = 0; t < 4; ++t) {
            acc2[t] = __builtin_amdgcn_mfma_f32_16x16x32_f16(A2a, B2f[t][0], acc2[t], 0, 0, 0);
            acc2[t] = __builtin_amdgcn_mfma_f32_16x16x32_f16(A2b, B2f[t][1], acc2[t], 0, 0, 0);
        }

        // Stage Y-tile [row][col] in LDS.
        #pragma unroll
        for (int t = 0; t < 4; ++t)
            #pragma unroll
            for (int i = 0; i < 4; ++i)
                ol[wv][q * 4 + i][t * 16 + l15] = fmaxf(acc2[t][i], 0.0f);

        // Degrees (clamped to listed slots).
        int dv = 0;
        if (r0 + l15 < N) {
            unsigned c = cnt[r0 + l15];
            dv = (int)(c < MAXDEG ? c : MAXDEG);
        }

        // Push each row to its edges: group q handles edge base+q.
        #pragma unroll
        for (int r = 0; r < 16; ++r) {
            const int deg = __builtin_amdgcn_readlane(dv, r);
            if (deg == 0) continue;  // wave-uniform
            const unsigned* sl = slots + (long long)(r0 + r) * MAXDEG;
            const f32x4 v = *(const f32x4*)&ol[wv][r][l15 * 4];
            for (int base = 0; base < deg; base += 4) {
                const int k = base + q;
                if (k < deg) {
                    const int eid = (int)sl[k];
                    *(f32x4*)&out[(long long)eid * 64 + l15 * 4] = v;
                }
            }
        }
    }

    // ---- overflow edges (expected none): per-edge MFMA, R8-style ----
    const int novf_raw = (int)ovfc[0];
    const int novf = novf_raw < OVF_CAP ? novf_raw : OVF_CAP;
    const int nt2 = (novf + 15) >> 4;
    for (int t2 = gw; t2 < nt2; t2 += nw) {
        const int i0 = t2 << 4;
        const int ii = (i0 + l15 < novf) ? (i0 + l15) : (novf - 1);
        const int e = (int)ovf[ii];
        const int n = src[e];
        const float* p = feat + (long long)n * 64;

        f16x8 A0, A1;
        {
            const f32x4 u0 = *(const f32x4*)(p + q * 8);
            const f32x4 u1 = *(const f32x4*)(p + q * 8 + 4);
            const f32x4 u2 = *(const f32x4*)(p + 32 + q * 8);
            const f32x4 u3 = *(const f32x4*)(p + 32 + q * 8 + 4);
            #pragma unroll
            for (int j = 0; j < 4; ++j) {
                A0[j] = (f16)u0[j]; A0[4 + j] = (f16)u1[j];
                A1[j] = (f16)u2[j]; A1[4 + j] = (f16)u3[j];
            }
        }

        f32x4 acc[4];
        #pragma unroll
        for (int t = 0; t < 4; ++t) acc[t] = (f32x4){bb1[t], bb1[t], bb1[t], bb1[t]};
        #pragma unroll
        for (int t = 0; t < 4; ++t) {
            acc[t] = __builtin_amdgcn_mfma_f32_16x16x32_f16(A0, B1f[t][0], acc[t], 0, 0, 0);
            acc[t] = __builtin_amdgcn_mfma_f32_16x16x32_f16(A1, B1f[t][1], acc[t], 0, 0, 0);
        }
        #pragma unroll
        for (int t = 0; t < 4; ++t)
            #pragma unroll
            for (int i = 0; i < 4; ++i)
                hl[wv][q * 4 + i][t * 16 + l15] = (f16)fmaxf(acc[t][i], 0.0f);

        const f16x8 A2a = *(const f16x8*)&hl[wv][l15][q * 8];
        const f16x8 A2b = *(const f16x8*)&hl[wv][l15][32 + q * 8];

        f32x4 acc2[4];
        #pragma unroll
        for (int t = 0; t < 4; ++t) acc2[t] = (f32x4){bb2[t], bb2[t], bb2[t], bb2[t]};
        #pragma unroll
        for (int t = 0; t < 4; ++t) {
            acc2[t] = __builtin_amdgcn_mfma_f32_16x16x32_f16(A2a, B2f[t][0], acc2[t], 0, 0, 0);
            acc2[t] = __builtin_amdgcn_mfma_f32_16x16x32_f16(A2b, B2f[t][1], acc2[t], 0, 0, 0);
        }

        se[wv][l15] = e;
        #pragma unroll
        for (int t = 0; t < 4; ++t)
            #pragma unroll
            for (int i2 = 0; i2 < 4; ++i2) {
                const int row = q * 4 + i2;
                if (i0 + row < novf) {
                    const int eid = se[wv][row];
                    out[(long long)eid * 64 + t * 16 + l15] = fmaxf(acc2[t][i2], 0.0f);
                }
            }
    }
}

// ---------------- Fallback (ws too small): per-edge readlane MLP ----------------
__device__ __forceinline__ float bcast_f(float v, int l) {
    return __int_as_float(__builtin_amdgcn_readlane(__float_as_int(v), l));
}

__global__ __launch_bounds__(256, 3) void mlp_nodes_kernel(
    const float* __restrict__ features,
    const int* __restrict__ idx,
    const float* __restrict__ W1, const float* __restrict__ b1,
    const float* __restrict__ W2, const float* __restrict__ b2,
    float* __restrict__ out, int nrows)
{
    const int lane   = threadIdx.x & 63;
    const int wid    = (blockIdx.x * blockDim.x + threadIdx.x) >> 6;
    const int nwaves = (gridDim.x * blockDim.x) >> 6;

    float w1c[64], w2c[64];
    #pragma unroll
    for (int k = 0; k < 64; ++k) w1c[k] = W1[k * 64 + lane];
    #pragma unroll
    for (int k = 0; k < 64; ++k) w2c[k] = W2[k * 64 + lane];
    const float hb = b1[lane];
    const float yb = b2[lane];

    for (int row = wid; row < nrows; row += nwaves) {
        const int n = idx ? idx[row] : row;
        const float x = features[(long long)n * 64 + lane];
        float a0 = hb, a1 = 0.f, a2 = 0.f, a3 = 0.f;
        #pragma unroll
        for (int k = 0; k < 64; k += 4) {
            a0 = fmaf(bcast_f(x, k + 0), w1c[k + 0], a0);
            a1 = fmaf(bcast_f(x, k + 1), w1c[k + 1], a1);
            a2 = fmaf(bcast_f(x, k + 2), w1c[k + 2], a2);
            a3 = fmaf(bcast_f(x, k + 3), w1c[k + 3], a3);
        }
        const float h = fmaxf((a0 + a1) + (a2 + a3), 0.0f);
        float c0 = yb, c1 = 0.f, c2 = 0.f, c3 = 0.f;
        #pragma unroll
        for (int k = 0; k < 64; k += 4) {
            c0 = fmaf(bcast_f(h, k + 0), w2c[k + 0], c0);
            c1 = fmaf(bcast_f(h, k + 1), w2c[k + 1], c1);
            c2 = fmaf(bcast_f(h, k + 2), w2c[k + 2], c2);
            c3 = fmaf(bcast_f(h, k + 3), w2c[k + 3], c3);
        }
        out[(long long)row * 64 + lane] = fmaxf((c0 + c1) + (c2 + c3), 0.0f);
    }
}

extern "C" void kernel_launch(void* const* d_in, const int* in_sizes, int n_in,
                              void* d_out, int out_size, void* d_ws, size_t ws_size,
                              hipStream_t stream) {
    const float* features = (const float*)d_in[0];
    const int*   src      = (const int*)  d_in[1];
    const float* W1       = (const float*)d_in[2];
    const float* b1       = (const float*)d_in[3];
    const float* W2       = (const float*)d_in[4];
    const float* b2       = (const float*)d_in[5];
    float* out = (float*)d_out;

    const int N = in_sizes[0] / 64;
    const int E = in_sizes[1];

    const size_t ws_words = (size_t)(N + 16) + (size_t)N * MAXDEG + OVF_CAP;
    if (ws_size >= ws_words * sizeof(unsigned)) {
        unsigned* cnt   = (unsigned*)d_ws;
        unsigned* ovfc  = cnt + N;
        unsigned* slots = cnt + N + 16;
        unsigned* ovf   = slots + (size_t)N * MAXDEG;

        // Zero counters (capture-safe async memset; harness uses the same API).
        hipMemsetAsync(d_ws, 0, (size_t)(N + 16) * sizeof(unsigned), stream);
        // Bucket edges by source node.
        fill_slots_kernel<<<1536, 256, 0, stream>>>(src, cnt, slots, ovf, ovfc, E);
        // Fused per-node MLP + edge broadcast (3128 waves vs 3125 tiles).
        bcast_kernel<<<782, 256, 0, stream>>>(
            features, src, W1, b1, W2, b2, cnt, slots, ovf, ovfc, out, N, E);
    } else {
        mlp_nodes_kernel<<<3072, 256, 0, stream>>>(
            features, src, W1, b1, W2, b2, out, E);
    }
}

// Round 12
// 63.397 us; speedup vs baseline: 1.8707x; 1.8707x over previous
//
#include <hip/hip_runtime.h>

typedef float f32x4 __attribute__((ext_vector_type(4)));
typedef _Float16 f16;
typedef f16 f16x8 __attribute__((ext_vector_type(8)));

// out[e] = relu(relu(features[src[e]] @ W1 + b1) @ W2 + b2)
// R8 structure (best measured: 66.1us): cvt features f32->f16 in ws, then
// fused per-edge gather + 2-layer MFMA MLP with coalesced 1KB stores.
// R11 change: output stores are NONTEMPORAL (no L2 allocate) so the 205MB
// write stream stops evicting the 6.4MB feat16 table from per-XCD L2.

// ---------------- features f32 -> f16 ----------------
__global__ __launch_bounds__(256) void cvt_kernel(
    const f32x4* __restrict__ in, f16x8* __restrict__ outv, int n8)
{
    const int stride = gridDim.x * blockDim.x;
    for (int i = blockIdx.x * blockDim.x + threadIdx.x; i < n8; i += stride) {
        const f32x4 a = in[2 * i];
        const f32x4 b = in[2 * i + 1];
        f16x8 o;
        #pragma unroll
        for (int j = 0; j < 4; ++j) { o[j] = (f16)a[j]; o[4 + j] = (f16)b[j]; }
        outv[i] = o;
    }
}

// ---------------- fused gather + MFMA MLP ----------------
// One wave computes a 16-edge x 64-col output tile. Layouts as verified in
// R6-R8 (A: row=l&15, k=(l>>4)*8+j+32s; B: k rows, col=16t+(l&15);
// D: col=l&15, row=(l>>4)*4+i). h transpose via wave-private LDS; output
// tile transposed via wave-private LDS then 4 x 1KB contiguous NT stores.
__global__ __launch_bounds__(256) void fused_mlp_kernel(
    const f16* __restrict__ feat16,  // [N][64]
    const int* __restrict__ src,     // [E]
    const float* __restrict__ W1, const float* __restrict__ b1,
    const float* __restrict__ W2, const float* __restrict__ b2,
    float* __restrict__ out, int E, int ntiles)
{
    __shared__ f16  hl[4][16][72];   // h staging, per wave
    __shared__ float ol[4][16][68];  // out-tile staging, per wave

    const int lane = threadIdx.x & 63;
    const int wv   = threadIdx.x >> 6;
    const int l15  = lane & 15;
    const int q    = lane >> 4;

    const int gw = blockIdx.x * 4 + wv;
    const int nw = gridDim.x * 4;

    // Weight fragments in registers for the whole kernel.
    f16x8 B1f[4][2], B2f[4][2];
    #pragma unroll
    for (int t = 0; t < 4; ++t) {
        #pragma unroll
        for (int s = 0; s < 2; ++s) {
            f16x8 r1, r2;
            #pragma unroll
            for (int j = 0; j < 8; ++j) {
                const int kk = s * 32 + q * 8 + j;
                r1[j] = (f16)W1[kk * 64 + t * 16 + l15];
                r2[j] = (f16)W2[kk * 64 + t * 16 + l15];
            }
            B1f[t][s] = r1;
            B2f[t][s] = r2;
        }
    }
    float bb1[4], bb2[4];
    #pragma unroll
    for (int t = 0; t < 4; ++t) {
        bb1[t] = b1[t * 16 + l15];
        bb2[t] = b2[t * 16 + l15];
    }

    int tile = gw;
    if (tile >= ntiles) return;

    // Preload tile 0's gather (src + A fragments).
    int er0 = tile * 16 + l15; if (er0 >= E) er0 = E - 1;
    int n = src[er0];
    const f16* fp0 = feat16 + (long long)n * 64;
    f16x8 A0 = *(const f16x8*)(fp0 + q * 8);
    f16x8 A1 = *(const f16x8*)(fp0 + 32 + q * 8);

    while (tile < ntiles) {
        const int e0 = tile * 16;
        const int tile_n = tile + nw;

        // Prefetch next tile's gather; latency hides under this tile's MFMAs.
        f16x8 nA0, nA1;
        if (tile_n < ntiles) {
            int er = tile_n * 16 + l15;
            if (er >= E) er = E - 1;
            const int nn = src[er];
            const f16* fp = feat16 + (long long)nn * 64;
            nA0 = *(const f16x8*)(fp + q * 8);
            nA1 = *(const f16x8*)(fp + 32 + q * 8);
        }

        // Layer 1: h = relu(x @ W1 + b1).
        f32x4 acc[4];
        #pragma unroll
        for (int t = 0; t < 4; ++t) acc[t] = (f32x4){bb1[t], bb1[t], bb1[t], bb1[t]};
        #pragma unroll
        for (int t = 0; t < 4; ++t) {
            acc[t] = __builtin_amdgcn_mfma_f32_16x16x32_f16(A0, B1f[t][0], acc[t], 0, 0, 0);
            acc[t] = __builtin_amdgcn_mfma_f32_16x16x32_f16(A1, B1f[t][1], acc[t], 0, 0, 0);
        }

        // relu + f16, stage h in wave-private LDS [row][col].
        #pragma unroll
        for (int t = 0; t < 4; ++t)
            #pragma unroll
            for (int i = 0; i < 4; ++i)
                hl[wv][q * 4 + i][t * 16 + l15] = (f16)fmaxf(acc[t][i], 0.0f);

        // A2: lane reads h[l15][s*32+q*8..+7] (16B ds_read_b128, same wave).
        const f16x8 A2a = *(const f16x8*)&hl[wv][l15][q * 8];
        const f16x8 A2b = *(const f16x8*)&hl[wv][l15][32 + q * 8];

        // Layer 2: y = relu(h @ W2 + b2).
        f32x4 acc2[4];
        #pragma unroll
        for (int t = 0; t < 4; ++t) acc2[t] = (f32x4){bb2[t], bb2[t], bb2[t], bb2[t]};
        #pragma unroll
        for (int t = 0; t < 4; ++t) {
            acc2[t] = __builtin_amdgcn_mfma_f32_16x16x32_f16(A2a, B2f[t][0], acc2[t], 0, 0, 0);
            acc2[t] = __builtin_amdgcn_mfma_f32_16x16x32_f16(A2b, B2f[t][1], acc2[t], 0, 0, 0);
        }

        if (e0 + 16 <= E) {
            // Stage relu(y) in LDS [row][col].
            #pragma unroll
            for (int t = 0; t < 4; ++t)
                #pragma unroll
                for (int i = 0; i < 4; ++i)
                    ol[wv][q * 4 + i][t * 16 + l15] = fmaxf(acc2[t][i], 0.0f);
            // 4 stores, each exactly 1KB contiguous, NONTEMPORAL (no L2 alloc).
            #pragma unroll
            for (int j = 0; j < 4; ++j) {
                const f32x4 v = *(const f32x4*)&ol[wv][4 * j + q][l15 * 4];
                __builtin_nontemporal_store(
                    v, (f32x4*)&out[(long long)(e0 + 4 * j + q) * 64 + l15 * 4]);
            }
        } else {
            // Tail tile: guarded scattered NT stores.
            #pragma unroll
            for (int t = 0; t < 4; ++t)
                #pragma unroll
                for (int i = 0; i < 4; ++i) {
                    const int row = e0 + q * 4 + i;
                    if (row < E)
                        __builtin_nontemporal_store(
                            fmaxf(acc2[t][i], 0.0f),
                            &out[(long long)row * 64 + t * 16 + l15]);
                }
        }

        A0 = nA0;
        A1 = nA1;
        tile = tile_n;
    }
}

// ---------------- Fallback (ws too small): per-edge readlane MLP ----------------
__device__ __forceinline__ float bcast_f(float v, int l) {
    return __int_as_float(__builtin_amdgcn_readlane(__float_as_int(v), l));
}

__global__ __launch_bounds__(256, 3) void mlp_nodes_kernel(
    const float* __restrict__ features,
    const int* __restrict__ idx,
    const float* __restrict__ W1, const float* __restrict__ b1,
    const float* __restrict__ W2, const float* __restrict__ b2,
    float* __restrict__ out, int nrows)
{
    const int lane   = threadIdx.x & 63;
    const int wid    = (blockIdx.x * blockDim.x + threadIdx.x) >> 6;
    const int nwaves = (gridDim.x * blockDim.x) >> 6;

    float w1c[64], w2c[64];
    #pragma unroll
    for (int k = 0; k < 64; ++k) w1c[k] = W1[k * 64 + lane];
    #pragma unroll
    for (int k = 0; k < 64; ++k) w2c[k] = W2[k * 64 + lane];
    const float hb = b1[lane];
    const float yb = b2[lane];

    for (int row = wid; row < nrows; row += nwaves) {
        const int n = idx ? idx[row] : row;
        const float x = features[(long long)n * 64 + lane];
        float a0 = hb, a1 = 0.f, a2 = 0.f, a3 = 0.f;
        #pragma unroll
        for (int k = 0; k < 64; k += 4) {
            a0 = fmaf(bcast_f(x, k + 0), w1c[k + 0], a0);
            a1 = fmaf(bcast_f(x, k + 1), w1c[k + 1], a1);
            a2 = fmaf(bcast_f(x, k + 2), w1c[k + 2], a2);
            a3 = fmaf(bcast_f(x, k + 3), w1c[k + 3], a3);
        }
        const float h = fmaxf((a0 + a1) + (a2 + a3), 0.0f);
        float c0 = yb, c1 = 0.f, c2 = 0.f, c3 = 0.f;
        #pragma unroll
        for (int k = 0; k < 64; k += 4) {
            c0 = fmaf(bcast_f(h, k + 0), w2c[k + 0], c0);
            c1 = fmaf(bcast_f(h, k + 1), w2c[k + 1], c1);
            c2 = fmaf(bcast_f(h, k + 2), w2c[k + 2], c2);
            c3 = fmaf(bcast_f(h, k + 3), w2c[k + 3], c3);
        }
        out[(long long)row * 64 + lane] = fmaxf((c0 + c1) + (c2 + c3), 0.0f);
    }
}

extern "C" void kernel_launch(void* const* d_in, const int* in_sizes, int n_in,
                              void* d_out, int out_size, void* d_ws, size_t ws_size,
                              hipStream_t stream) {
    const float* features = (const float*)d_in[0];
    const int*   src      = (const int*)  d_in[1];
    const float* W1       = (const float*)d_in[2];
    const float* b1       = (const float*)d_in[3];
    const float* W2       = (const float*)d_in[4];
    const float* b2       = (const float*)d_in[5];
    float* out = (float*)d_out;

    const int N = in_sizes[0] / 64;
    const int E = in_sizes[1];

    const size_t need = (size_t)N * 64 * sizeof(f16);
    if (ws_size >= need) {
        f16* feat16 = (f16*)d_ws;
        cvt_kernel<<<1024, 256, 0, stream>>>(
            (const f32x4*)features, (f16x8*)feat16, N * 8);
        const int ntiles = (E + 15) / 16;
        // 1024 blocks x 4 waves = 4096 waves, ~12 tiles/wave.
        fused_mlp_kernel<<<1024, 256, 0, stream>>>(
            feat16, src, W1, b1, W2, b2, out, E, ntiles);
    } else {
        mlp_nodes_kernel<<<3072, 256, 0, stream>>>(
            features, src, W1, b1, W2, b2, out, E);
    }
}

// Round 13
// 54.789 us; speedup vs baseline: 2.1646x; 1.1571x over previous
//
#include <hip/hip_runtime.h>

typedef float f32x4 __attribute__((ext_vector_type(4)));
typedef _Float16 f16;
typedef f16 f16x8 __attribute__((ext_vector_type(8)));

// out[e] = relu(relu(features[src[e]] @ W1 + b1) @ W2 + b2)
// R12 structure (63.4us) + R13 change: 2-tile software pipeline in the fused
// kernel — 2-deep gather prefetch, unroll-by-2 tile loop, per-parity h-LDS
// slices so two tiles' MFMA chains can interleave.

// ---------------- features f32 -> f16 ----------------
__global__ __launch_bounds__(256) void cvt_kernel(
    const f32x4* __restrict__ in, f16x8* __restrict__ outv, int n8)
{
    const int stride = gridDim.x * blockDim.x;
    for (int i = blockIdx.x * blockDim.x + threadIdx.x; i < n8; i += stride) {
        const f32x4 a = in[2 * i];
        const f32x4 b = in[2 * i + 1];
        f16x8 o;
        #pragma unroll
        for (int j = 0; j < 4; ++j) { o[j] = (f16)a[j]; o[4 + j] = (f16)b[j]; }
        outv[i] = o;
    }
}

// ---------------- fused gather + MFMA MLP, 2-tile pipelined ----------------
// Layouts as verified R6-R12. One wave = one 16-edge x 64-col tile per stage.
__global__ __launch_bounds__(256) void fused_mlp_kernel(
    const f16* __restrict__ feat16,  // [N][64]
    const int* __restrict__ src,     // [E]
    const float* __restrict__ W1, const float* __restrict__ b1,
    const float* __restrict__ W2, const float* __restrict__ b2,
    float* __restrict__ out, int E, int ntiles)
{
    __shared__ f16   hl[2][4][16][72];  // h staging, per parity x per wave
    __shared__ float ol[4][16][68];     // out-tile staging, per wave

    const int lane = threadIdx.x & 63;
    const int wv   = threadIdx.x >> 6;
    const int l15  = lane & 15;
    const int q    = lane >> 4;

    const int gw = blockIdx.x * 4 + wv;
    const int nw = gridDim.x * 4;

    // Weight fragments in registers for the whole kernel (64 VGPRs).
    f16x8 B1f[4][2], B2f[4][2];
    #pragma unroll
    for (int t = 0; t < 4; ++t) {
        #pragma unroll
        for (int s = 0; s < 2; ++s) {
            f16x8 r1, r2;
            #pragma unroll
            for (int j = 0; j < 8; ++j) {
                const int kk = s * 32 + q * 8 + j;
                r1[j] = (f16)W1[kk * 64 + t * 16 + l15];
                r2[j] = (f16)W2[kk * 64 + t * 16 + l15];
            }
            B1f[t][s] = r1;
            B2f[t][s] = r2;
        }
    }
    float bb1[4], bb2[4];
    #pragma unroll
    for (int t = 0; t < 4; ++t) {
        bb1[t] = b1[t * 16 + l15];
        bb2[t] = b2[t * 16 + l15];
    }

    auto LOADFRAG = [&](int tile, f16x8& A0, f16x8& A1) {
        int er = tile * 16 + l15;
        if (er >= E) er = E - 1;
        const int nn = src[er];
        const f16* fp = feat16 + (long long)nn * 64;
        A0 = *(const f16x8*)(fp + q * 8);
        A1 = *(const f16x8*)(fp + 32 + q * 8);
    };

    auto COMPUTE = [&](int tile, int par, const f16x8& A0, const f16x8& A1) {
        const int e0 = tile * 16;

        // Layer 1: h = relu(x @ W1 + b1).
        f32x4 acc[4];
        #pragma unroll
        for (int t = 0; t < 4; ++t) acc[t] = (f32x4){bb1[t], bb1[t], bb1[t], bb1[t]};
        #pragma unroll
        for (int t = 0; t < 4; ++t) {
            acc[t] = __builtin_amdgcn_mfma_f32_16x16x32_f16(A0, B1f[t][0], acc[t], 0, 0, 0);
            acc[t] = __builtin_amdgcn_mfma_f32_16x16x32_f16(A1, B1f[t][1], acc[t], 0, 0, 0);
        }

        // relu + f16, stage h in per-parity wave-private LDS [row][col].
        #pragma unroll
        for (int t = 0; t < 4; ++t)
            #pragma unroll
            for (int i = 0; i < 4; ++i)
                hl[par][wv][q * 4 + i][t * 16 + l15] = (f16)fmaxf(acc[t][i], 0.0f);

        // A2: lane reads h[l15][s*32+q*8..+7] (16B ds_read_b128, same wave).
        const f16x8 A2a = *(const f16x8*)&hl[par][wv][l15][q * 8];
        const f16x8 A2b = *(const f16x8*)&hl[par][wv][l15][32 + q * 8];

        // Layer 2: y = relu(h @ W2 + b2).
        f32x4 acc2[4];
        #pragma unroll
        for (int t = 0; t < 4; ++t) acc2[t] = (f32x4){bb2[t], bb2[t], bb2[t], bb2[t]};
        #pragma unroll
        for (int t = 0; t < 4; ++t) {
            acc2[t] = __builtin_amdgcn_mfma_f32_16x16x32_f16(A2a, B2f[t][0], acc2[t], 0, 0, 0);
            acc2[t] = __builtin_amdgcn_mfma_f32_16x16x32_f16(A2b, B2f[t][1], acc2[t], 0, 0, 0);
        }

        if (e0 + 16 <= E) {
            // Stage relu(y) in LDS [row][col]; then 4 x 1KB contiguous NT stores.
            #pragma unroll
            for (int t = 0; t < 4; ++t)
                #pragma unroll
                for (int i = 0; i < 4; ++i)
                    ol[wv][q * 4 + i][t * 16 + l15] = fmaxf(acc2[t][i], 0.0f);
            #pragma unroll
            for (int j = 0; j < 4; ++j) {
                const f32x4 v = *(const f32x4*)&ol[wv][4 * j + q][l15 * 4];
                __builtin_nontemporal_store(
                    v, (f32x4*)&out[(long long)(e0 + 4 * j + q) * 64 + l15 * 4]);
            }
        } else {
            #pragma unroll
            for (int t = 0; t < 4; ++t)
                #pragma unroll
                for (int i = 0; i < 4; ++i) {
                    const int row = e0 + q * 4 + i;
                    if (row < E)
                        __builtin_nontemporal_store(
                            fmaxf(acc2[t][i], 0.0f),
                            &out[(long long)row * 64 + t * 16 + l15]);
                }
        }
    };

    const int t0 = gw;
    if (t0 >= ntiles) return;

    // 2-deep prologue.
    f16x8 P0a, P0b, P1a, P1b, Ca, Cb, Da, Db;
    LOADFRAG(t0, P0a, P0b);
    {
        const int tB = t0 + nw;
        LOADFRAG(tB < ntiles ? tB : ntiles - 1, P1a, P1b);
    }

    const int step2 = 2 * nw;
    for (int t = t0; t < ntiles; t += step2) {
        const int tA = t, tB = t + nw;
        const int tC = t + step2, tD = t + step2 + nw;

        // Issue prefetches for the NEXT unrolled pair, then compute this pair.
        LOADFRAG(tC < ntiles ? tC : ntiles - 1, Ca, Cb);
        COMPUTE(tA, 0, P0a, P0b);
        LOADFRAG(tD < ntiles ? tD : ntiles - 1, Da, Db);
        if (tB < ntiles) COMPUTE(tB, 1, P1a, P1b);

        P0a = Ca; P0b = Cb;
        P1a = Da; P1b = Db;
    }
}

// ---------------- Fallback (ws too small): per-edge readlane MLP ----------------
__device__ __forceinline__ float bcast_f(float v, int l) {
    return __int_as_float(__builtin_amdgcn_readlane(__float_as_int(v), l));
}

__global__ __launch_bounds__(256, 3) void mlp_nodes_kernel(
    const float* __restrict__ features,
    const int* __restrict__ idx,
    const float* __restrict__ W1, const float* __restrict__ b1,
    const float* __restrict__ W2, const float* __restrict__ b2,
    float* __restrict__ out, int nrows)
{
    const int lane   = threadIdx.x & 63;
    const int wid    = (blockIdx.x * blockDim.x + threadIdx.x) >> 6;
    const int nwaves = (gridDim.x * blockDim.x) >> 6;

    float w1c[64], w2c[64];
    #pragma unroll
    for (int k = 0; k < 64; ++k) w1c[k] = W1[k * 64 + lane];
    #pragma unroll
    for (int k = 0; k < 64; ++k) w2c[k] = W2[k * 64 + lane];
    const float hb = b1[lane];
    const float yb = b2[lane];

    for (int row = wid; row < nrows; row += nwaves) {
        const int n = idx ? idx[row] : row;
        const float x = features[(long long)n * 64 + lane];
        float a0 = hb, a1 = 0.f, a2 = 0.f, a3 = 0.f;
        #pragma unroll
        for (int k = 0; k < 64; k += 4) {
            a0 = fmaf(bcast_f(x, k + 0), w1c[k + 0], a0);
            a1 = fmaf(bcast_f(x, k + 1), w1c[k + 1], a1);
            a2 = fmaf(bcast_f(x, k + 2), w1c[k + 2], a2);
            a3 = fmaf(bcast_f(x, k + 3), w1c[k + 3], a3);
        }
        const float h = fmaxf((a0 + a1) + (a2 + a3), 0.0f);
        float c0 = yb, c1 = 0.f, c2 = 0.f, c3 = 0.f;
        #pragma unroll
        for (int k = 0; k < 64; k += 4) {
            c0 = fmaf(bcast_f(h, k + 0), w2c[k + 0], c0);
            c1 = fmaf(bcast_f(h, k + 1), w2c[k + 1], c1);
            c2 = fmaf(bcast_f(h, k + 2), w2c[k + 2], c2);
            c3 = fmaf(bcast_f(h, k + 3), w2c[k + 3], c3);
        }
        out[(long long)row * 64 + lane] = fmaxf((c0 + c1) + (c2 + c3), 0.0f);
    }
}

extern "C" void kernel_launch(void* const* d_in, const int* in_sizes, int n_in,
                              void* d_out, int out_size, void* d_ws, size_t ws_size,
                              hipStream_t stream) {
    const float* features = (const float*)d_in[0];
    const int*   src      = (const int*)  d_in[1];
    const float* W1       = (const float*)d_in[2];
    const float* b1       = (const float*)d_in[3];
    const float* W2       = (const float*)d_in[4];
    const float* b2       = (const float*)d_in[5];
    float* out = (float*)d_out;

    const int N = in_sizes[0] / 64;
    const int E = in_sizes[1];

    const size_t need = (size_t)N * 64 * sizeof(f16);
    if (ws_size >= need) {
        f16* feat16 = (f16*)d_ws;
        cvt_kernel<<<1024, 256, 0, stream>>>(
            (const f32x4*)features, (f16x8*)feat16, N * 8);
        const int ntiles = (E + 15) / 16;
        // 1024 blocks x 4 waves = 4096 waves, ~12 tiles/wave, 2-deep pipeline.
        fused_mlp_kernel<<<1024, 256, 0, stream>>>(
            feat16, src, W1, b1, W2, b2, out, E, ntiles);
    } else {
        mlp_nodes_kernel<<<3072, 256, 0, stream>>>(
            features, src, W1, b1, W2, b2, out, E);
    }
}

// Round 14
// 54.517 us; speedup vs baseline: 2.1753x; 1.0050x over previous
//
#include <hip/hip_runtime.h>

typedef float f32x4 __attribute__((ext_vector_type(4)));
typedef _Float16 f16;
typedef f16 f16x8 __attribute__((ext_vector_type(8)));

// out[e] = relu(relu(features[src[e]] @ W1 + b1) @ W2 + b2)
// R13 structure (54.8us) + R14 change: decoupled 2-level prefetch —
// src indices fetched 4 tiles ahead (regs sA/sB), feature rows fetched
// 2 tiles ahead from already-resident indices. Breaks the serial
// src->row dependency at issue time.

// ---------------- features f32 -> f16 ----------------
__global__ __launch_bounds__(256) void cvt_kernel(
    const f32x4* __restrict__ in, f16x8* __restrict__ outv, int n8)
{
    const int stride = gridDim.x * blockDim.x;
    for (int i = blockIdx.x * blockDim.x + threadIdx.x; i < n8; i += stride) {
        const f32x4 a = in[2 * i];
        const f32x4 b = in[2 * i + 1];
        f16x8 o;
        #pragma unroll
        for (int j = 0; j < 4; ++j) { o[j] = (f16)a[j]; o[4 + j] = (f16)b[j]; }
        outv[i] = o;
    }
}

// ---------------- fused gather + MFMA MLP, 2-tile pipeline, split prefetch ----
__global__ __launch_bounds__(256) void fused_mlp_kernel(
    const f16* __restrict__ feat16,  // [N][64]
    const int* __restrict__ src,     // [E]
    const float* __restrict__ W1, const float* __restrict__ b1,
    const float* __restrict__ W2, const float* __restrict__ b2,
    float* __restrict__ out, int E, int ntiles)
{
    __shared__ f16   hl[2][4][16][72];  // h staging, per parity x per wave
    __shared__ float ol[4][16][68];     // out-tile staging, per wave

    const int lane = threadIdx.x & 63;
    const int wv   = threadIdx.x >> 6;
    const int l15  = lane & 15;
    const int q    = lane >> 4;

    const int gw = blockIdx.x * 4 + wv;
    const int nw = gridDim.x * 4;

    // Weight fragments in registers for the whole kernel (64 VGPRs).
    f16x8 B1f[4][2], B2f[4][2];
    #pragma unroll
    for (int t = 0; t < 4; ++t) {
        #pragma unroll
        for (int s = 0; s < 2; ++s) {
            f16x8 r1, r2;
            #pragma unroll
            for (int j = 0; j < 8; ++j) {
                const int kk = s * 32 + q * 8 + j;
                r1[j] = (f16)W1[kk * 64 + t * 16 + l15];
                r2[j] = (f16)W2[kk * 64 + t * 16 + l15];
            }
            B1f[t][s] = r1;
            B2f[t][s] = r2;
        }
    }
    float bb1[4], bb2[4];
    #pragma unroll
    for (int t = 0; t < 4; ++t) {
        bb1[t] = b1[t * 16 + l15];
        bb2[t] = b2[t * 16 + l15];
    }

    // src index for this lane's row of a tile (clamped).
    auto LOADSRC = [&](int tile) -> int {
        int er = tile * 16 + l15;
        if (er >= E) er = E - 1;
        return src[er];
    };
    // feature-row fragments from an already-resident node index.
    auto LOADROWS = [&](int nn, f16x8& A0, f16x8& A1) {
        const f16* fp = feat16 + (long long)nn * 64;
        A0 = *(const f16x8*)(fp + q * 8);
        A1 = *(const f16x8*)(fp + 32 + q * 8);
    };

    auto COMPUTE = [&](int tile, int par, const f16x8& A0, const f16x8& A1) {
        const int e0 = tile * 16;

        // Layer 1: h = relu(x @ W1 + b1).
        f32x4 acc[4];
        #pragma unroll
        for (int t = 0; t < 4; ++t) acc[t] = (f32x4){bb1[t], bb1[t], bb1[t], bb1[t]};
        #pragma unroll
        for (int t = 0; t < 4; ++t) {
            acc[t] = __builtin_amdgcn_mfma_f32_16x16x32_f16(A0, B1f[t][0], acc[t], 0, 0, 0);
            acc[t] = __builtin_amdgcn_mfma_f32_16x16x32_f16(A1, B1f[t][1], acc[t], 0, 0, 0);
        }

        // relu + f16, stage h in per-parity wave-private LDS [row][col].
        #pragma unroll
        for (int t = 0; t < 4; ++t)
            #pragma unroll
            for (int i = 0; i < 4; ++i)
                hl[par][wv][q * 4 + i][t * 16 + l15] = (f16)fmaxf(acc[t][i], 0.0f);

        // A2: lane reads h[l15][s*32+q*8..+7] (16B ds_read_b128, same wave).
        const f16x8 A2a = *(const f16x8*)&hl[par][wv][l15][q * 8];
        const f16x8 A2b = *(const f16x8*)&hl[par][wv][l15][32 + q * 8];

        // Layer 2: y = relu(h @ W2 + b2).
        f32x4 acc2[4];
        #pragma unroll
        for (int t = 0; t < 4; ++t) acc2[t] = (f32x4){bb2[t], bb2[t], bb2[t], bb2[t]};
        #pragma unroll
        for (int t = 0; t < 4; ++t) {
            acc2[t] = __builtin_amdgcn_mfma_f32_16x16x32_f16(A2a, B2f[t][0], acc2[t], 0, 0, 0);
            acc2[t] = __builtin_amdgcn_mfma_f32_16x16x32_f16(A2b, B2f[t][1], acc2[t], 0, 0, 0);
        }

        if (e0 + 16 <= E) {
            // Stage relu(y) in LDS [row][col]; then 4 x 1KB contiguous NT stores.
            #pragma unroll
            for (int t = 0; t < 4; ++t)
                #pragma unroll
                for (int i = 0; i < 4; ++i)
                    ol[wv][q * 4 + i][t * 16 + l15] = fmaxf(acc2[t][i], 0.0f);
            #pragma unroll
            for (int j = 0; j < 4; ++j) {
                const f32x4 v = *(const f32x4*)&ol[wv][4 * j + q][l15 * 4];
                __builtin_nontemporal_store(
                    v, (f32x4*)&out[(long long)(e0 + 4 * j + q) * 64 + l15 * 4]);
            }
        } else {
            #pragma unroll
            for (int t = 0; t < 4; ++t)
                #pragma unroll
                for (int i = 0; i < 4; ++i) {
                    const int row = e0 + q * 4 + i;
                    if (row < E)
                        __builtin_nontemporal_store(
                            fmaxf(acc2[t][i], 0.0f),
                            &out[(long long)row * 64 + t * 16 + l15]);
                }
        }
    };

    const int t0 = gw;
    if (t0 >= ntiles) return;
    const int step2 = 2 * nw;
    const int clampT = ntiles - 1;

    // Prologue: src for pair 0, rows for pair 0, src for pair 1.
    int sA = LOADSRC(t0);
    int sB = LOADSRC(t0 + nw <= clampT ? t0 + nw : clampT);
    f16x8 P0a, P0b, P1a, P1b, Ca, Cb, Da, Db;
    LOADROWS(sA, P0a, P0b);
    LOADROWS(sB, P1a, P1b);
    {
        int tC = t0 + step2;     if (tC > clampT) tC = clampT;
        int tD = t0 + step2 + nw; if (tD > clampT) tD = clampT;
        sA = LOADSRC(tC);
        sB = LOADSRC(tD);
    }

    for (int t = t0; t < ntiles; t += step2) {
        const int tA = t, tB = t + nw;

        // src prefetch for pair+2 (independent of everything below).
        int tE = t + 2 * step2;      if (tE > clampT) tE = clampT;
        int tF = t + 2 * step2 + nw; if (tF > clampT) tF = clampT;
        const int nE = LOADSRC(tE);
        const int nF = LOADSRC(tF);

        // row prefetch for pair+1 from already-resident indices.
        LOADROWS(sA, Ca, Cb);
        LOADROWS(sB, Da, Db);

        COMPUTE(tA, 0, P0a, P0b);
        if (tB < ntiles) COMPUTE(tB, 1, P1a, P1b);

        sA = nE; sB = nF;
        P0a = Ca; P0b = Cb;
        P1a = Da; P1b = Db;
    }
}

// ---------------- Fallback (ws too small): per-edge readlane MLP ----------------
__device__ __forceinline__ float bcast_f(float v, int l) {
    return __int_as_float(__builtin_amdgcn_readlane(__float_as_int(v), l));
}

__global__ __launch_bounds__(256, 3) void mlp_nodes_kernel(
    const float* __restrict__ features,
    const int* __restrict__ idx,
    const float* __restrict__ W1, const float* __restrict__ b1,
    const float* __restrict__ W2, const float* __restrict__ b2,
    float* __restrict__ out, int nrows)
{
    const int lane   = threadIdx.x & 63;
    const int wid    = (blockIdx.x * blockDim.x + threadIdx.x) >> 6;
    const int nwaves = (gridDim.x * blockDim.x) >> 6;

    float w1c[64], w2c[64];
    #pragma unroll
    for (int k = 0; k < 64; ++k) w1c[k] = W1[k * 64 + lane];
    #pragma unroll
    for (int k = 0; k < 64; ++k) w2c[k] = W2[k * 64 + lane];
    const float hb = b1[lane];
    const float yb = b2[lane];

    for (int row = wid; row < nrows; row += nwaves) {
        const int n = idx ? idx[row] : row;
        const float x = features[(long long)n * 64 + lane];
        float a0 = hb, a1 = 0.f, a2 = 0.f, a3 = 0.f;
        #pragma unroll
        for (int k = 0; k < 64; k += 4) {
            a0 = fmaf(bcast_f(x, k + 0), w1c[k + 0], a0);
            a1 = fmaf(bcast_f(x, k + 1), w1c[k + 1], a1);
            a2 = fmaf(bcast_f(x, k + 2), w1c[k + 2], a2);
            a3 = fmaf(bcast_f(x, k + 3), w1c[k + 3], a3);
        }
        const float h = fmaxf((a0 + a1) + (a2 + a3), 0.0f);
        float c0 = yb, c1 = 0.f, c2 = 0.f, c3 = 0.f;
        #pragma unroll
        for (int k = 0; k < 64; k += 4) {
            c0 = fmaf(bcast_f(h, k + 0), w2c[k + 0], c0);
            c1 = fmaf(bcast_f(h, k + 1), w2c[k + 1], c1);
            c2 = fmaf(bcast_f(h, k + 2), w2c[k + 2], c2);
            c3 = fmaf(bcast_f(h, k + 3), w2c[k + 3], c3);
        }
        out[(long long)row * 64 + lane] = fmaxf((c0 + c1) + (c2 + c3), 0.0f);
    }
}

extern "C" void kernel_launch(void* const* d_in, const int* in_sizes, int n_in,
                              void* d_out, int out_size, void* d_ws, size_t ws_size,
                              hipStream_t stream) {
    const float* features = (const float*)d_in[0];
    const int*   src      = (const int*)  d_in[1];
    const float* W1       = (const float*)d_in[2];
    const float* b1       = (const float*)d_in[3];
    const float* W2       = (const float*)d_in[4];
    const float* b2       = (const float*)d_in[5];
    float* out = (float*)d_out;

    const int N = in_sizes[0] / 64;
    const int E = in_sizes[1];

    const size_t need = (size_t)N * 64 * sizeof(f16);
    if (ws_size >= need) {
        f16* feat16 = (f16*)d_ws;
        cvt_kernel<<<1024, 256, 0, stream>>>(
            (const f32x4*)features, (f16x8*)feat16, N * 8);
        const int ntiles = (E + 15) / 16;
        // 1024 blocks x 4 waves = 4096 waves, ~12 tiles/wave.
        fused_mlp_kernel<<<1024, 256, 0, stream>>>(
            feat16, src, W1, b1, W2, b2, out, E, ntiles);
    } else {
        mlp_nodes_kernel<<<3072, 256, 0, stream>>>(
            features, src, W1, b1, W2, b2, out, E);
    }
}